// Round 5
// baseline (341.799 us; speedup 1.0000x reference)
//
#include <hip/hip_runtime.h>
#include <hip/hip_bf16.h>

// TransposedLocallyConnected2D: out[b,o,l] = sum_d U[b,d,l] * W[d,l,o] + bias[o,l]
//   B=64, C=64, OC=128, L=1024, D=576 (d = c*9 + tap). Per-l 64x128x576 GEMM.
//
// R5 structure (R4 was latency-bound: 18 barrier-locked LDS-W rounds, VALUBusy 2.5%):
//  k1 wt_kernel: w f32 -> wt bf16 in B-FRAGMENT-DIRECT layout
//     wt16B[(l*18 + kt)*512 + nt*64 + g*16 + r] = W[32kt+8g+i][l][16nt+r], i=0..7.
//     (B-frag lane map n=lane&15, k=8*(lane>>4)+i was HW-verified by R4 passing.)
//  k2 mfma_kernel: block per l, wave wv owns o in [32wv,32wv+32) (nt = 2wv, 2wv+1).
//     B-frags read DIRECTLY from global wt, 1KB coalesced per fragment, 1-deep
//     register double-buffer (compiler emits counted vmcnt). NO k-loop barriers.
//     U chunk (64b x 288k bf16) in LDS; A-frags via ds_read_b128 per kt.
//  k3 out_kernel: ws[l][o][b] -> out[b][o][l] + bias (R4-verified).

typedef __attribute__((ext_vector_type(8))) short bf16x8;
typedef __attribute__((ext_vector_type(4))) float f32x4;
typedef __attribute__((ext_vector_type(4))) unsigned short us4;
typedef __attribute__((ext_vector_type(8))) unsigned short us8;

#define UROW 296   // U chunk row stride bf16: 288 data + 8 pad (592 B = 37*16)

__device__ __forceinline__ unsigned short f2bf(float f) {
    union { __hip_bfloat16 h; unsigned short u; } cv;
    cv.h = __float2bfloat16(f);
    return cv.u;
}

// ---------------------------------------------------------------- kernel 1
// grid (18, 1024): blockIdx.x = kt, blockIdx.y = l. 32d x 128o per block.
__global__ __launch_bounds__(256, 8)
void wt_kernel(const float* __restrict__ w, unsigned short* __restrict__ wt)
{
    __shared__ unsigned short T[32][132];   // [d-local][o], +4 pad
    const int kt = blockIdx.x;
    const int l  = blockIdx.y;
    const int t  = threadIdx.x;

    // read: rows d = 32kt + dl, 512B contiguous per row, cvt to bf16
    {
        const int o4 = t & 31;              // o = 4*o4
        #pragma unroll
        for (int it = 0; it < 4; ++it) {
            const int dl = (t >> 5) + 8 * it;
            const float4 v = *(const float4*)(
                w + (size_t)(32 * kt + dl) * 131072 + (size_t)l * 128 + 4 * o4);
            *(us4*)&T[dl][4 * o4] = (us4){f2bf(v.x), f2bf(v.y), f2bf(v.z), f2bf(v.w)};
        }
    }
    __syncthreads();

    // write: fragment f = nt*64 + g*16 + r; bytes 16 per f; 1KB contiguous per nt
    {
        char* dst = (char*)wt + (size_t)(l * 18 + kt) * 8192;
        #pragma unroll
        for (int half = 0; half < 2; ++half) {
            const int f  = t + 256 * half;
            const int nt = f >> 6;
            const int g  = (f >> 4) & 3;
            const int r  = f & 15;
            us8 v;
            #pragma unroll
            for (int i = 0; i < 8; ++i)
                v[i] = T[8 * g + i][16 * nt + r];
            *(us8*)(dst + f * 16) = v;
        }
    }
}

// ---------------------------------------------------------------- kernel 2
template <bool WSPATH>
__global__ __launch_bounds__(256, 4)
void mfma_kernel(const float* __restrict__ x,
                 const unsigned short* __restrict__ wt,
                 const float* __restrict__ bias,
                 float* __restrict__ wsout,
                 float* __restrict__ out)
{
    __shared__ unsigned short smem[64 * UROW];   // 37,888 B (U chunk only)

    const int blk  = blockIdx.x;
    const int l    = ((blk & 7) << 7) | (blk >> 3);   // bijective XCD swizzle
    const int oh   = l >> 5, ow = l & 31;
    const int tid  = threadIdx.x;
    const int lane = tid & 63;
    const int wv   = tid >> 6;      // wave owns o in [32wv, 32wv+32)
    const int r    = lane & 15;
    const int g    = lane >> 4;

    const char* wbase = (const char*)wt + (size_t)l * 147456;   // 18*8192
    const int   foff  = 2048 * wv + lane * 16;                  // nt=2wv frag offset

    f32x4 acc[4][2];
    #pragma unroll
    for (int mt = 0; mt < 4; ++mt) {
        acc[mt][0] = (f32x4){0.f, 0.f, 0.f, 0.f};
        acc[mt][1] = (f32x4){0.f, 0.f, 0.f, 0.f};
    }

    #pragma unroll
    for (int c2 = 0; c2 < 2; ++c2) {
        // ---- issue first B-fragment loads of this chunk (in flight during U-stage)
        const char* kp = wbase + (size_t)(9 * c2) * 8192 + foff;
        bf16x8 bc0 = *(const bf16x8*)kp;
        bf16x8 bc1 = *(const bf16x8*)(kp + 1024);

        // ---- stage U chunk c2: d-local = c_local*9 + tap, c = 32c2 + c_local
        {
            const int sb  = tid & 63;
            const int scg = tid >> 6;
            #pragma unroll
            for (int cl = 0; cl < 8; ++cl) {
                const int c = c2 * 32 + scg * 8 + cl;
                const float* xp = x + ((size_t)(sb * 64 + c) << 10);
                unsigned short* ur = smem + sb * UROW + (scg * 8 + cl) * 9;
                #pragma unroll
                for (int ii = 0; ii < 3; ++ii) {
                    const int y = oh + ii - 1;
                    const bool yok = (unsigned)y < 32u;
                    #pragma unroll
                    for (int jj = 0; jj < 3; ++jj) {
                        const int z = ow + jj - 1;
                        float v = (yok && ((unsigned)z < 32u)) ? xp[(y << 5) + z] : 0.f;
                        ur[ii * 3 + jj] = f2bf(v);
                    }
                }
            }
        }
        __syncthreads();

        // ---- 9 k-tiles: barrier-free, register-double-buffered B stream
        #pragma unroll
        for (int ktl = 0; ktl < 9; ++ktl) {
            bf16x8 bn0 = bc0, bn1 = bc1;
            if (ktl < 8) {
                const char* np = wbase + (size_t)(9 * c2 + ktl + 1) * 8192 + foff;
                bn0 = *(const bf16x8*)np;
                bn1 = *(const bf16x8*)(np + 1024);
            }
            bf16x8 a[4];
            #pragma unroll
            for (int mt = 0; mt < 4; ++mt)
                a[mt] = *(const bf16x8*)(smem + (16 * mt + r) * UROW + ktl * 32 + g * 8);
            #pragma unroll
            for (int mt = 0; mt < 4; ++mt) {
                acc[mt][0] = __builtin_amdgcn_mfma_f32_16x16x32_bf16(a[mt], bc0, acc[mt][0], 0, 0, 0);
                acc[mt][1] = __builtin_amdgcn_mfma_f32_16x16x32_bf16(a[mt], bc1, acc[mt][1], 0, 0, 0);
            }
            bc0 = bn0; bc1 = bn1;
        }
        __syncthreads();   // all waves done reading U before restage / exit
    }

    // ---- epilogue: acc[mt][n] elem q -> b = 16mt + 4g + q, o = (2wv+n)*16 + r
    if (WSPATH) {
        float* wsp = wsout + ((size_t)l << 13);
        #pragma unroll
        for (int n = 0; n < 2; ++n) {
            const int o = (2 * wv + n) * 16 + r;
            #pragma unroll
            for (int mt = 0; mt < 4; ++mt)
                *(f32x4*)(wsp + o * 64 + 16 * mt + 4 * g) = acc[mt][n];
        }
    } else {
        #pragma unroll
        for (int n = 0; n < 2; ++n) {
            const int o = (2 * wv + n) * 16 + r;
            const float bz = bias[(o << 10) + l];
            #pragma unroll
            for (int mt = 0; mt < 4; ++mt)
                #pragma unroll
                for (int q = 0; q < 4; ++q) {
                    const int b = 16 * mt + 4 * g + q;
                    out[((size_t)(b * 128 + o) << 10) + l] = acc[mt][n][q] + bz;
                }
        }
    }
}

// ---------------------------------------------------------------- kernel 3
// ws[l][o][b] -> out[b][o][l] (+bias), tiles [32 l][16 o][16 b]  (R4-verified)
__global__ __launch_bounds__(256, 4)
void out_kernel(const float* __restrict__ ws,
                const float* __restrict__ bias,
                float* __restrict__ out)
{
    __shared__ float Ls[32 * 16 * 16];
    const int blk = blockIdx.x;
    const int b0 = (blk & 3) * 16;
    const int o0 = ((blk >> 2) & 7) * 16;
    const int l0 = (blk >> 5) * 32;
    const int t  = threadIdx.x;

    const int b4  = (t & 3) * 4;
    const int o   = (t >> 2) & 15;
    const int lr0 = t >> 6;
    #pragma unroll
    for (int p = 0; p < 8; ++p) {
        const int lr = lr0 + 4 * p;
        const f32x4 v = *(const f32x4*)(ws + (size_t)(l0 + lr) * 8192 + (o0 + o) * 64 + b0 + b4);
        *(f32x4*)(&Ls[(lr * 16 + o) * 16 + b4]) = v;
    }
    __syncthreads();

    const int lq = (t & 7) * 4;
    #pragma unroll
    for (int p = 0; p < 8; ++p) {
        const int row   = p * 32 + (t >> 3);
        const int o_loc = row >> 4;
        const int b_loc = row & 15;
        f32x4 v;
        #pragma unroll
        for (int q = 0; q < 4; ++q)
            v[q] = Ls[((lq + q) * 16 + o_loc) * 16 + b_loc];
        const f32x4 bz = *(const f32x4*)(bias + (o0 + o_loc) * 1024 + l0 + lq);
        v += bz;
        *(f32x4*)(out + ((size_t)((b0 + b_loc) * 128) + o0 + o_loc) * 1024 + l0 + lq) = v;
    }
}

// ---------------------------------------------------------------- fp32 fallback (R1-verified)
__global__ __launch_bounds__(256, 4)
void lc2d_fp32(const float* __restrict__ x,
               const float* __restrict__ w,
               const float* __restrict__ bias,
               float* __restrict__ out)
{
    __shared__ float Us[36][68];
    __shared__ float Ws[36][128];
    const int blk = blockIdx.x;
    const int l  = ((blk & 7) << 7) | (blk >> 3);
    const int oh = l >> 5, ow = l & 31;
    const int tid = threadIdx.x;
    const int tx = tid & 15, ty = tid >> 4;
    const int sb = tid >> 2, sc = tid & 3;

    float acc[4][8];
    #pragma unroll
    for (int i = 0; i < 4; ++i)
        #pragma unroll
        for (int j = 0; j < 8; ++j) acc[i][j] = 0.f;

    for (int ch = 0; ch < 16; ++ch) {
        const int c0 = ch * 4;
        const float* xb = x + ((size_t)(sb * 64 + c0 + sc) << 10);
        #pragma unroll
        for (int ii = 0; ii < 3; ++ii) {
            const int y = oh + ii - 1;
            const bool yok = ((unsigned)y < 32u);
            #pragma unroll
            for (int jj = 0; jj < 3; ++jj) {
                const int z = ow + jj - 1;
                float v = 0.f;
                if (yok && ((unsigned)z < 32u)) v = xb[(y << 5) + z];
                Us[sc * 9 + ii * 3 + jj][sb] = v;
            }
        }
        const int dbase = c0 * 9;
        #pragma unroll
        for (int it = 0; it < 5; ++it) {
            const int idx = tid + it * 256;
            if (idx < 36 * 32) {
                const int kk = idx >> 5, o4 = idx & 31;
                const float4 v = *reinterpret_cast<const float4*>(
                    w + (((size_t)(dbase + kk) * 1024 + l) * 128 + o4 * 4));
                *reinterpret_cast<float4*>(&Ws[kk][o4 * 4]) = v;
            }
        }
        __syncthreads();
        #pragma unroll 6
        for (int kk = 0; kk < 36; ++kk) {
            const float4 ub = *reinterpret_cast<const float4*>(&Us[kk][ty * 4]);
            const float4 wa = *reinterpret_cast<const float4*>(&Ws[kk][tx * 4]);
            const float4 wb = *reinterpret_cast<const float4*>(&Ws[kk][tx * 4 + 64]);
            const float u[4]  = {ub.x, ub.y, ub.z, ub.w};
            const float a[4]  = {wa.x, wa.y, wa.z, wa.w};
            const float b2[4] = {wb.x, wb.y, wb.z, wb.w};
            #pragma unroll
            for (int bi = 0; bi < 4; ++bi)
                #pragma unroll
                for (int oi = 0; oi < 4; ++oi) {
                    acc[bi][oi]     += u[bi] * a[oi];
                    acc[bi][4 + oi] += u[bi] * b2[oi];
                }
        }
        __syncthreads();
    }

    float bs[8];
    #pragma unroll
    for (int oi = 0; oi < 4; ++oi) {
        bs[oi]     = bias[((tx * 4 + oi) << 10) + l];
        bs[4 + oi] = bias[((tx * 4 + 64 + oi) << 10) + l];
    }
    #pragma unroll
    for (int bi = 0; bi < 4; ++bi) {
        const int b = ty * 4 + bi;
        #pragma unroll
        for (int oi = 0; oi < 4; ++oi) {
            out[((b * 128 + tx * 4 + oi) << 10) + l]      = acc[bi][oi]     + bs[oi];
            out[((b * 128 + tx * 4 + 64 + oi) << 10) + l] = acc[bi][4 + oi] + bs[4 + oi];
        }
    }
}

// ---------------------------------------------------------------- launch
extern "C" void kernel_launch(void* const* d_in, const int* in_sizes, int n_in,
                              void* d_out, int out_size, void* d_ws, size_t ws_size,
                              hipStream_t stream) {
    const float* x    = (const float*)d_in[0];
    const float* w    = (const float*)d_in[1];
    const float* bias = (const float*)d_in[2];
    float* out        = (float*)d_out;

    const size_t WT_BYTES  = 1024ull * 18 * 8192;      // 150,994,944
    const size_t WSO_BYTES = 64ull * 128 * 1024 * 4;   // 33,554,432

    if (d_ws && ws_size >= WT_BYTES + WSO_BYTES) {
        unsigned short* wtb = (unsigned short*)d_ws;
        float* wso = (float*)((char*)d_ws + WT_BYTES);
        wt_kernel<<<dim3(18, 1024), dim3(256), 0, stream>>>(w, wtb);
        mfma_kernel<true><<<dim3(1024), dim3(256), 0, stream>>>(x, wtb, bias, wso, out);
        out_kernel<<<dim3(1024), dim3(256), 0, stream>>>(wso, bias, out);
    } else if (d_ws && ws_size >= WT_BYTES) {
        unsigned short* wtb = (unsigned short*)d_ws;
        wt_kernel<<<dim3(18, 1024), dim3(256), 0, stream>>>(w, wtb);
        mfma_kernel<false><<<dim3(1024), dim3(256), 0, stream>>>(x, wtb, bias, nullptr, out);
    } else {
        lc2d_fp32<<<dim3(1024), dim3(256), 0, stream>>>(x, w, bias, out);
    }
}

// Round 6
// 226.147 us; speedup vs baseline: 1.5114x; 1.5114x over previous
//
#include <hip/hip_runtime.h>
#include <hip/hip_bf16.h>

// TransposedLocallyConnected2D: out[b,o,l] = sum_d U[b,d,l] * W[d,l,o] + bias[o,l]
//   B=64, C=64, OC=128, L=1024, D=576 (d = c*9 + ii*3 + jj). Per-l 64x128x576 GEMM.
//
// R6: the proven bottleneck was the per-l scattered x gather (~800MB of 64B-granule
// L2/L3 traffic) + compiler-collapsed prefetch. New structure:
//  k1 u_kernel: x -> uA bf16, A-FRAGMENT-DIRECT layout:
//     uA16B[(((oh*4+mt)*16+r)*72 + ks)*32 + ow] = U[b=16mt+r][k=8ks+e][l=oh*32+ow]
//     Coalesced x reads (LDS stage), coalesced 512B fragment writes. 17MB R, 75.5MB W.
//  k2 mfma_kernel: NO LDS, NO barriers. Per l-block, wave wv owns o[32wv,32wv+32).
//     A-frags 16B/lane from uA; W read f32 in native layout (lane(r,g): 64B per
//     16-lane group), cvt->bf16 in-reg. Register double-buffer pinned with
//     sched_barrier(0). 8 MFMA/kt. ws[l][o][b] full-line stores.
//  k3 out_kernel: ws -> out[b][o][l] + bias (R4/R5-verified).

typedef __attribute__((ext_vector_type(8))) short bf16x8;
typedef __attribute__((ext_vector_type(4))) float f32x4;
typedef __attribute__((ext_vector_type(4))) unsigned short us4;
typedef __attribute__((ext_vector_type(8))) unsigned short us8;

__device__ __forceinline__ unsigned short f2bf(float f) {
    union { __hip_bfloat16 h; unsigned short u; } cv;
    cv.h = __float2bfloat16(f);
    return cv.u;
}

// ---------------------------------------------------------------- kernel 1
// grid 256: blk -> ch (c-half), bg (b-quarter), oh. LDS-staged coalesced x read,
// per-thread k-row gather, fragment-direct coalesced writes.
__global__ __launch_bounds__(256, 1)
void u_kernel(const float* __restrict__ x, unsigned short* __restrict__ uA)
{
    __shared__ unsigned short xs[3 * 32 * 16 * 36];   // [y][c][b][32z + 4 pad] 110.6KB

    const int blk = blockIdx.x;
    const int ch = blk & 1;          // c in [32ch, 32ch+32)
    const int bg = (blk >> 1) & 3;   // b in [16bg, 16bg+16)  (mt = bg)
    const int oh = blk >> 3;
    const int t  = threadIdx.x;

    // ---- stage x chunk: 16b x 32c x 3y x 32z, fully coalesced float4
    #pragma unroll
    for (int y = 0; y < 3; ++y) {
        const int yg = oh - 1 + y;
        const bool rowok = (unsigned)yg < 32u;   // block-uniform
        #pragma unroll
        for (int j = 0; j < 16; ++j) {
            const int idx2 = t + 256 * j;
            const int z4 = idx2 & 7;
            const int cl = (idx2 >> 3) & 31;
            const int bl = idx2 >> 8;
            float4 v = {0.f, 0.f, 0.f, 0.f};
            if (rowok)
                v = *(const float4*)(x + ((((16 * bg + bl) * 64 + 32 * ch + cl) * 32 + yg) << 5) + 4 * z4);
            *(us4*)&xs[((y * 32 + cl) * 16 + bl) * 36 + 4 * z4] =
                (us4){f2bf(v.x), f2bf(v.y), f2bf(v.z), f2bf(v.w)};
        }
    }
    __syncthreads();

    // ---- gather: item (ow, b_local); emit k-rows in fragment-direct order
    #pragma unroll
    for (int p = 0; p < 2; ++p) {
        const int item = t + 256 * p;
        const int ow = item & 31;
        const int bl = item >> 5;
        #pragma unroll
        for (int cc = 0; cc < 2; ++cc) {
            us8 arr[18];
            #pragma unroll
            for (int c16 = 0; c16 < 16; ++c16) {
                const int c = cc * 16 + c16;
                #pragma unroll
                for (int ii = 0; ii < 3; ++ii) {
                    const unsigned short* xr = &xs[((ii * 32 + c) * 16 + bl) * 36];
                    const unsigned short vm = (ow > 0)  ? xr[ow - 1] : (unsigned short)0;
                    const unsigned short v0 = xr[ow];
                    const unsigned short vp = (ow < 31) ? xr[ow + 1] : (unsigned short)0;
                    const int f = c16 * 9 + ii * 3;      // compile-time after unroll
                    arr[(f + 0) >> 3][(f + 0) & 7] = vm;
                    arr[(f + 1) >> 3][(f + 1) & 7] = v0;
                    arr[(f + 2) >> 3][(f + 2) & 7] = vp;
                }
            }
            // write 18 x us8: ks = 36ch + 18cc + j
            char* dst = (char*)uA +
                ((((size_t)(oh * 4 + bg) * 16 + bl) * 72 + (36 * ch + 18 * cc)) * 32 + ow) * 16;
            #pragma unroll
            for (int j = 0; j < 18; ++j)
                *(us8*)(dst + (size_t)j * 512) = arr[j];
        }
    }
}

// ---------------------------------------------------------------- kernel 2
template <bool WSPATH>
__global__ __launch_bounds__(256, 4)
void mfma_kernel(const unsigned short* __restrict__ uA,
                 const float* __restrict__ w,
                 const float* __restrict__ bias,
                 float* __restrict__ wsout,
                 float* __restrict__ out)
{
    const int blk  = blockIdx.x;
    const int l    = ((blk & 7) << 7) | (blk >> 3);   // adjacent l -> same XCD
    const int oh   = l >> 5, ow = l & 31;
    const int tid  = threadIdx.x;
    const int lane = tid & 63;
    const int wv   = tid >> 6;      // wave owns o in [32wv, 32wv+32)
    const int r    = lane & 15;
    const int g    = lane >> 4;

    // W lane base: element (d = 8g, o = 32wv + r); d-stride 131072 elems
    const float* wp = w + (size_t)(8 * g) * 131072 + (size_t)l * 128 + 32 * wv + r;
    // uA lane base (ushort units): mt-stride 294912, kt-stride 1024
    const unsigned short* up = uA +
        ((((size_t)oh * 4 * 16 + r) * 72 + g) * 32 + ow) * 8;

    f32x4 acc[4][2];
    #pragma unroll
    for (int mt = 0; mt < 4; ++mt) {
        acc[mt][0] = (f32x4){0.f, 0.f, 0.f, 0.f};
        acc[mt][1] = (f32x4){0.f, 0.f, 0.f, 0.f};
    }

#define LOADK(KT, U_, WA_, WB_)                                               \
    {                                                                         \
        _Pragma("unroll")                                                     \
        for (int mt = 0; mt < 4; ++mt)                                        \
            U_[mt] = *(const bf16x8*)(up + (size_t)(KT) * 1024 + (size_t)mt * 294912); \
        _Pragma("unroll")                                                     \
        for (int i = 0; i < 8; ++i) {                                         \
            WA_[i] = wp[(size_t)((KT) * 32 + i) * 131072];                    \
            WB_[i] = wp[(size_t)((KT) * 32 + i) * 131072 + 16];               \
        }                                                                     \
    }

    bf16x8 cu[4];
    float  cwa[8], cwb[8];
    LOADK(0, cu, cwa, cwb);

    #pragma unroll
    for (int kt = 0; kt < 18; ++kt) {
        bf16x8 nu[4] = {};
        float  nwa[8] = {}, nwb[8] = {};
        if (kt < 17)
            LOADK(kt + 1, nu, nwa, nwb);
        __builtin_amdgcn_sched_barrier(0);   // pin prefetch before compute

        us8 fb0, fb1;
        #pragma unroll
        for (int i = 0; i < 8; ++i) { fb0[i] = f2bf(cwa[i]); fb1[i] = f2bf(cwb[i]); }
        union { us8 u; bf16x8 b; } c0, c1;
        c0.u = fb0; c1.u = fb1;
        #pragma unroll
        for (int mt = 0; mt < 4; ++mt) {
            acc[mt][0] = __builtin_amdgcn_mfma_f32_16x16x32_bf16(cu[mt], c0.b, acc[mt][0], 0, 0, 0);
            acc[mt][1] = __builtin_amdgcn_mfma_f32_16x16x32_bf16(cu[mt], c1.b, acc[mt][1], 0, 0, 0);
        }

        #pragma unroll
        for (int mt = 0; mt < 4; ++mt) cu[mt] = nu[mt];
        #pragma unroll
        for (int i = 0; i < 8; ++i) { cwa[i] = nwa[i]; cwb[i] = nwb[i]; }
    }
#undef LOADK

    // ---- epilogue: acc[mt][n] elem q -> b = 16mt + 4g + q, o = (2wv+n)*16 + r
    if (WSPATH) {
        float* wsp = wsout + ((size_t)l << 13);
        #pragma unroll
        for (int n = 0; n < 2; ++n) {
            const int o = (2 * wv + n) * 16 + r;
            #pragma unroll
            for (int mt = 0; mt < 4; ++mt)
                *(f32x4*)(wsp + o * 64 + 16 * mt + 4 * g) = acc[mt][n];
        }
    } else {
        #pragma unroll
        for (int n = 0; n < 2; ++n) {
            const int o = (2 * wv + n) * 16 + r;
            const float bz = bias[(o << 10) + l];
            #pragma unroll
            for (int mt = 0; mt < 4; ++mt)
                #pragma unroll
                for (int q = 0; q < 4; ++q) {
                    const int b = 16 * mt + 4 * g + q;
                    out[((size_t)(b * 128 + o) << 10) + l] = acc[mt][n][q] + bz;
                }
        }
    }
}

// ---------------------------------------------------------------- kernel 3
// ws[l][o][b] -> out[b][o][l] (+bias), tiles [32 l][16 o][16 b]  (verified)
__global__ __launch_bounds__(256, 4)
void out_kernel(const float* __restrict__ ws,
                const float* __restrict__ bias,
                float* __restrict__ out)
{
    __shared__ float Ls[32 * 16 * 16];
    const int blk = blockIdx.x;
    const int b0 = (blk & 3) * 16;
    const int o0 = ((blk >> 2) & 7) * 16;
    const int l0 = (blk >> 5) * 32;
    const int t  = threadIdx.x;

    const int b4  = (t & 3) * 4;
    const int o   = (t >> 2) & 15;
    const int lr0 = t >> 6;
    #pragma unroll
    for (int p = 0; p < 8; ++p) {
        const int lr = lr0 + 4 * p;
        const f32x4 v = *(const f32x4*)(ws + (size_t)(l0 + lr) * 8192 + (o0 + o) * 64 + b0 + b4);
        *(f32x4*)(&Ls[(lr * 16 + o) * 16 + b4]) = v;
    }
    __syncthreads();

    const int lq = (t & 7) * 4;
    #pragma unroll
    for (int p = 0; p < 8; ++p) {
        const int row   = p * 32 + (t >> 3);
        const int o_loc = row >> 4;
        const int b_loc = row & 15;
        f32x4 v;
        #pragma unroll
        for (int q = 0; q < 4; ++q)
            v[q] = Ls[((lq + q) * 16 + o_loc) * 16 + b_loc];
        const f32x4 bz = *(const f32x4*)(bias + (o0 + o_loc) * 1024 + l0 + lq);
        v += bz;
        *(f32x4*)(out + ((size_t)((b0 + b_loc) * 128) + o0 + o_loc) * 1024 + l0 + lq) = v;
    }
}

// ---------------------------------------------------------------- fp32 fallback (R1-verified)
__global__ __launch_bounds__(256, 4)
void lc2d_fp32(const float* __restrict__ x,
               const float* __restrict__ w,
               const float* __restrict__ bias,
               float* __restrict__ out)
{
    __shared__ float Us[36][68];
    __shared__ float Ws[36][128];
    const int blk = blockIdx.x;
    const int l  = ((blk & 7) << 7) | (blk >> 3);
    const int oh = l >> 5, ow = l & 31;
    const int tid = threadIdx.x;
    const int tx = tid & 15, ty = tid >> 4;
    const int sb = tid >> 2, sc = tid & 3;

    float acc[4][8];
    #pragma unroll
    for (int i = 0; i < 4; ++i)
        #pragma unroll
        for (int j = 0; j < 8; ++j) acc[i][j] = 0.f;

    for (int chn = 0; chn < 16; ++chn) {
        const int c0 = chn * 4;
        const float* xb = x + ((size_t)(sb * 64 + c0 + sc) << 10);
        #pragma unroll
        for (int ii = 0; ii < 3; ++ii) {
            const int y = oh + ii - 1;
            const bool yok = ((unsigned)y < 32u);
            #pragma unroll
            for (int jj = 0; jj < 3; ++jj) {
                const int z = ow + jj - 1;
                float v = 0.f;
                if (yok && ((unsigned)z < 32u)) v = xb[(y << 5) + z];
                Us[sc * 9 + ii * 3 + jj][sb] = v;
            }
        }
        const int dbase = c0 * 9;
        #pragma unroll
        for (int it = 0; it < 5; ++it) {
            const int idx = tid + it * 256;
            if (idx < 36 * 32) {
                const int kk = idx >> 5, o4 = idx & 31;
                const float4 v = *reinterpret_cast<const float4*>(
                    w + (((size_t)(dbase + kk) * 1024 + l) * 128 + o4 * 4));
                *reinterpret_cast<float4*>(&Ws[kk][o4 * 4]) = v;
            }
        }
        __syncthreads();
        #pragma unroll 6
        for (int kk = 0; kk < 36; ++kk) {
            const float4 ub = *reinterpret_cast<const float4*>(&Us[kk][ty * 4]);
            const float4 wa = *reinterpret_cast<const float4*>(&Ws[kk][tx * 4]);
            const float4 wb = *reinterpret_cast<const float4*>(&Ws[kk][tx * 4 + 64]);
            const float u[4]  = {ub.x, ub.y, ub.z, ub.w};
            const float a[4]  = {wa.x, wa.y, wa.z, wa.w};
            const float b2[4] = {wb.x, wb.y, wb.z, wb.w};
            #pragma unroll
            for (int bi = 0; bi < 4; ++bi)
                #pragma unroll
                for (int oi = 0; oi < 4; ++oi) {
                    acc[bi][oi]     += u[bi] * a[oi];
                    acc[bi][4 + oi] += u[bi] * b2[oi];
                }
        }
        __syncthreads();
    }

    float bs[8];
    #pragma unroll
    for (int oi = 0; oi < 4; ++oi) {
        bs[oi]     = bias[((tx * 4 + oi) << 10) + l];
        bs[4 + oi] = bias[((tx * 4 + 64 + oi) << 10) + l];
    }
    #pragma unroll
    for (int bi = 0; bi < 4; ++bi) {
        const int b = ty * 4 + bi;
        #pragma unroll
        for (int oi = 0; oi < 4; ++oi) {
            out[((b * 128 + tx * 4 + oi) << 10) + l]      = acc[bi][oi]     + bs[oi];
            out[((b * 128 + tx * 4 + 64 + oi) << 10) + l] = acc[bi][4 + oi] + bs[4 + oi];
        }
    }
}

// ---------------------------------------------------------------- launch
extern "C" void kernel_launch(void* const* d_in, const int* in_sizes, int n_in,
                              void* d_out, int out_size, void* d_ws, size_t ws_size,
                              hipStream_t stream) {
    const float* x    = (const float*)d_in[0];
    const float* w    = (const float*)d_in[1];
    const float* bias = (const float*)d_in[2];
    float* out        = (float*)d_out;

    const size_t UA_BYTES  = 75497472ull;   // 32*4*16*72*32 * 16
    const size_t WSO_BYTES = 33554432ull;   // 64*128*1024 * 4

    if (d_ws && ws_size >= UA_BYTES + WSO_BYTES) {
        unsigned short* uab = (unsigned short*)d_ws;
        float* wso = (float*)((char*)d_ws + UA_BYTES);
        u_kernel<<<dim3(256), dim3(256), 0, stream>>>(x, uab);
        mfma_kernel<true><<<dim3(1024), dim3(256), 0, stream>>>(uab, w, bias, wso, out);
        out_kernel<<<dim3(1024), dim3(256), 0, stream>>>(wso, bias, out);
    } else if (d_ws && ws_size >= UA_BYTES) {
        unsigned short* uab = (unsigned short*)d_ws;
        u_kernel<<<dim3(256), dim3(256), 0, stream>>>(x, uab);
        mfma_kernel<false><<<dim3(1024), dim3(256), 0, stream>>>(uab, w, bias, nullptr, out);
    } else {
        lc2d_fp32<<<dim3(1024), dim3(256), 0, stream>>>(x, w, bias, out);
    }
}

// Round 7
// 163.147 us; speedup vs baseline: 2.0950x; 1.3862x over previous
//
#include <hip/hip_runtime.h>
#include <hip/hip_bf16.h>

// TransposedLocallyConnected2D: out[b,o,l] = sum_d U[b,d,l] * W[d,l,o] + bias[o,l]
//   B=64, C=64, OC=128, L=1024, D=576 (d = c*9 + ii*3 + jj). Per-l 64x128x576 GEMM.
//
// R7: all-rounds-consistent theory = scattered-lane loads (64 lines/instr) choke
// the CU request pipe. Fixes: (a) uA layout v2 so A-frag loads are 4x256B segments
// and u_kernel stores are 1KB wave-contiguous; (b) 512-thr blocks, wave=4mt x 1nt
// (acc 16 VGPR -> fits 64-VGPR/32-wave occupancy tier), no W redundancy;
// (c) split-K=2 (grid 2048) with 2 ws slabs summed in out_kernel.
//
// uA byte layout: cell[(oh*4+mt)*18 + kt][g] of 8192B, inside: (ow*16 + r)*16.
//   uA frag(mt,kt,g,r | l) = U[b=16mt+r][k=32kt+8g+e][l], e=0..7 (bf16 us8).

typedef __attribute__((ext_vector_type(8))) short bf16x8;
typedef __attribute__((ext_vector_type(4))) float f32x4;
typedef __attribute__((ext_vector_type(4))) unsigned short us4;
typedef __attribute__((ext_vector_type(8))) unsigned short us8;

__device__ __forceinline__ unsigned short f2bf(float f) {
    union { __hip_bfloat16 h; unsigned short u; } cv;
    cv.h = __float2bfloat16(f);
    return cv.u;
}

// ---------------------------------------------------------------- kernel 1
// grid 256: blk -> ch (c-half), bg (b-quarter = mt), oh.
__global__ __launch_bounds__(256, 1)
void u_kernel(const float* __restrict__ x, unsigned short* __restrict__ uA)
{
    __shared__ unsigned short xs[3 * 32 * 16 * 36];   // [y][c][b][32z + 4 pad]

    const int blk = blockIdx.x;
    const int ch = blk & 1;          // c in [32ch, 32ch+32)
    const int bg = (blk >> 1) & 3;   // b in [16bg, 16bg+16)  (mt = bg)
    const int oh = blk >> 3;
    const int t  = threadIdx.x;

    // ---- stage x chunk: 16b x 32c x 3y x 32z, fully coalesced float4 (R6-verified)
    #pragma unroll
    for (int y = 0; y < 3; ++y) {
        const int yg = oh - 1 + y;
        const bool rowok = (unsigned)yg < 32u;   // block-uniform
        #pragma unroll
        for (int j = 0; j < 16; ++j) {
            const int idx2 = t + 256 * j;
            const int z4 = idx2 & 7;
            const int cl = (idx2 >> 3) & 31;
            const int bl = idx2 >> 8;
            float4 v = {0.f, 0.f, 0.f, 0.f};
            if (rowok)
                v = *(const float4*)(x + ((((16 * bg + bl) * 64 + 32 * ch + cl) * 32 + yg) << 5) + 4 * z4);
            *(us4*)&xs[((y * 32 + cl) * 16 + bl) * 36 + 4 * z4] =
                (us4){f2bf(v.x), f2bf(v.y), f2bf(v.z), f2bf(v.w)};
        }
    }
    __syncthreads();

    // ---- gather: item (bl = t&15, ow = t>>4 + 16p)  -> 1KB-contiguous wave stores
    const int bl = t & 15;
    #pragma unroll
    for (int p = 0; p < 2; ++p) {
        const int ow = (t >> 4) + 16 * p;
        #pragma unroll
        for (int cc = 0; cc < 2; ++cc) {
            us8 arr[18];
            #pragma unroll
            for (int c16 = 0; c16 < 16; ++c16) {
                const int c = cc * 16 + c16;
                #pragma unroll
                for (int ii = 0; ii < 3; ++ii) {
                    const unsigned short* xr = &xs[((ii * 32 + c) * 16 + bl) * 36];
                    const unsigned short vm = (ow > 0)  ? xr[ow - 1] : (unsigned short)0;
                    const unsigned short v0 = xr[ow];
                    const unsigned short vp = (ow < 31) ? xr[ow + 1] : (unsigned short)0;
                    const int f = c16 * 9 + ii * 3;      // compile-time after unroll
                    arr[(f + 0) >> 3][(f + 0) & 7] = vm;
                    arr[(f + 1) >> 3][(f + 1) & 7] = v0;
                    arr[(f + 2) >> 3][(f + 2) & 7] = vp;
                }
            }
            // ks = 36ch + 18cc + j; kt = ks>>2, g = ks&3
            char* base = (char*)uA + (size_t)(oh * 4 + bg) * 589824 + (ow * 16 + bl) * 16;
            #pragma unroll
            for (int j = 0; j < 18; ++j) {
                const int ks = 36 * ch + 18 * cc + j;
                *(us8*)(base + (size_t)(ks >> 2) * 32768 + (size_t)(ks & 3) * 8192) = arr[j];
            }
        }
    }
}

// ---------------------------------------------------------------- kernel 2
// 512 threads = 8 waves; wave wvn owns o in [16wvn, 16wvn+16); acc[4] = 4 mt.
template <bool WSPATH, bool SPLIT>
__global__ __launch_bounds__(512, 8)
void mfma_kernel(const unsigned short* __restrict__ uA,
                 const float* __restrict__ w,
                 const float* __restrict__ bias,
                 float* __restrict__ wsout,
                 float* __restrict__ out)
{
    constexpr int NKT = SPLIT ? 9 : 18;
    const int blk  = blockIdx.x;
    const int kh   = SPLIT ? (blk & 1) : 0;
    const int lq   = SPLIT ? (blk >> 1) : blk;
    const int l    = ((lq & 7) << 7) | (lq >> 3);   // bijective XCD swizzle
    const int oh   = l >> 5, ow = l & 31;
    const int tid  = threadIdx.x;
    const int lane = tid & 63;
    const int wvn  = tid >> 6;      // 0..7
    const int r    = lane & 15;
    const int g    = lane >> 4;

    // W: lane(r,g) reads W[d = 288kh + 32ktl + 8g + i][l][o = 16wvn + r]
    const float* wp = w + ((size_t)(288 * kh) + 8 * g) * 131072
                        + (size_t)l * 128 + 16 * wvn + r;
    // uA: 4-segment fragment reads (256B per 16-lane group)
    const char* up = (const char*)uA + (size_t)(oh * 4) * 589824
                     + (size_t)(9 * kh) * 32768 + g * 8192 + (ow * 16 + r) * 16;

    f32x4 acc[4];
    #pragma unroll
    for (int mt = 0; mt < 4; ++mt) acc[mt] = (f32x4){0.f, 0.f, 0.f, 0.f};

    #pragma unroll
    for (int ktl = 0; ktl < NKT; ++ktl) {
        bf16x8 cu[4];
        #pragma unroll
        for (int mt = 0; mt < 4; ++mt)
            cu[mt] = *(const bf16x8*)(up + (size_t)mt * 589824 + (size_t)ktl * 32768);
        us8 fb;
        #pragma unroll
        for (int i = 0; i < 8; ++i)
            fb[i] = f2bf(wp[(size_t)(ktl * 32 + i) * 131072]);
        union { us8 u; bf16x8 b; } cb;
        cb.u = fb;
        #pragma unroll
        for (int mt = 0; mt < 4; ++mt)
            acc[mt] = __builtin_amdgcn_mfma_f32_16x16x32_bf16(cu[mt], cb.b, acc[mt], 0, 0, 0);
    }

    // epilogue: acc[mt] elem q -> b = 16mt + 4g + q, o = 16wvn + r
    const int o = 16 * wvn + r;
    if (WSPATH) {
        float* wsp = wsout + (size_t)kh * 8388608 + ((size_t)l << 13) + o * 64 + 4 * g;
        #pragma unroll
        for (int mt = 0; mt < 4; ++mt)
            *(f32x4*)(wsp + 16 * mt) = acc[mt];
    } else {
        const float bz = bias[(o << 10) + l];
        #pragma unroll
        for (int mt = 0; mt < 4; ++mt)
            #pragma unroll
            for (int q = 0; q < 4; ++q) {
                const int b = 16 * mt + 4 * g + q;
                out[((size_t)(b * 128 + o) << 10) + l] = acc[mt][q] + bz;
            }
    }
}

// ---------------------------------------------------------------- kernel 3
// ws[kh][l][o][b] -> out[b][o][l] (+bias), tiles [32 l][16 o][16 b]
template <int NSLAB>
__global__ __launch_bounds__(256, 4)
void out_kernel(const float* __restrict__ ws,
                const float* __restrict__ bias,
                float* __restrict__ out)
{
    __shared__ float Ls[32 * 16 * 16];
    const int blk = blockIdx.x;
    const int b0 = (blk & 3) * 16;
    const int o0 = ((blk >> 2) & 7) * 16;
    const int l0 = (blk >> 5) * 32;
    const int t  = threadIdx.x;

    const int b4  = (t & 3) * 4;
    const int o   = (t >> 2) & 15;
    const int lr0 = t >> 6;
    #pragma unroll
    for (int p = 0; p < 8; ++p) {
        const int lr = lr0 + 4 * p;
        const size_t off = (size_t)(l0 + lr) * 8192 + (o0 + o) * 64 + b0 + b4;
        f32x4 v = *(const f32x4*)(ws + off);
        if (NSLAB == 2)
            v += *(const f32x4*)(ws + 8388608 + off);
        *(f32x4*)(&Ls[(lr * 16 + o) * 16 + b4]) = v;
    }
    __syncthreads();

    const int lq = (t & 7) * 4;
    #pragma unroll
    for (int p = 0; p < 8; ++p) {
        const int row   = p * 32 + (t >> 3);
        const int o_loc = row >> 4;
        const int b_loc = row & 15;
        f32x4 v;
        #pragma unroll
        for (int q = 0; q < 4; ++q)
            v[q] = Ls[((lq + q) * 16 + o_loc) * 16 + b_loc];
        const f32x4 bz = *(const f32x4*)(bias + (o0 + o_loc) * 1024 + l0 + lq);
        v += bz;
        *(f32x4*)(out + ((size_t)((b0 + b_loc) * 128) + o0 + o_loc) * 1024 + l0 + lq) = v;
    }
}

// ---------------------------------------------------------------- fp32 fallback (R1-verified)
__global__ __launch_bounds__(256, 4)
void lc2d_fp32(const float* __restrict__ x,
               const float* __restrict__ w,
               const float* __restrict__ bias,
               float* __restrict__ out)
{
    __shared__ float Us[36][68];
    __shared__ float Ws[36][128];
    const int blk = blockIdx.x;
    const int l  = ((blk & 7) << 7) | (blk >> 3);
    const int oh = l >> 5, ow = l & 31;
    const int tid = threadIdx.x;
    const int tx = tid & 15, ty = tid >> 4;
    const int sb = tid >> 2, sc = tid & 3;

    float acc[4][8];
    #pragma unroll
    for (int i = 0; i < 4; ++i)
        #pragma unroll
        for (int j = 0; j < 8; ++j) acc[i][j] = 0.f;

    for (int chn = 0; chn < 16; ++chn) {
        const int c0 = chn * 4;
        const float* xb = x + ((size_t)(sb * 64 + c0 + sc) << 10);
        #pragma unroll
        for (int ii = 0; ii < 3; ++ii) {
            const int y = oh + ii - 1;
            const bool yok = ((unsigned)y < 32u);
            #pragma unroll
            for (int jj = 0; jj < 3; ++jj) {
                const int z = ow + jj - 1;
                float v = 0.f;
                if (yok && ((unsigned)z < 32u)) v = xb[(y << 5) + z];
                Us[sc * 9 + ii * 3 + jj][sb] = v;
            }
        }
        const int dbase = c0 * 9;
        #pragma unroll
        for (int it = 0; it < 5; ++it) {
            const int idx = tid + it * 256;
            if (idx < 36 * 32) {
                const int kk = idx >> 5, o4 = idx & 31;
                const float4 v = *reinterpret_cast<const float4*>(
                    w + (((size_t)(dbase + kk) * 1024 + l) * 128 + o4 * 4));
                *reinterpret_cast<float4*>(&Ws[kk][o4 * 4]) = v;
            }
        }
        __syncthreads();
        #pragma unroll 6
        for (int kk = 0; kk < 36; ++kk) {
            const float4 ub = *reinterpret_cast<const float4*>(&Us[kk][ty * 4]);
            const float4 wa = *reinterpret_cast<const float4*>(&Ws[kk][tx * 4]);
            const float4 wb = *reinterpret_cast<const float4*>(&Ws[kk][tx * 4 + 64]);
            const float u[4]  = {ub.x, ub.y, ub.z, ub.w};
            const float a[4]  = {wa.x, wa.y, wa.z, wa.w};
            const float b2[4] = {wb.x, wb.y, wb.z, wb.w};
            #pragma unroll
            for (int bi = 0; bi < 4; ++bi)
                #pragma unroll
                for (int oi = 0; oi < 4; ++oi) {
                    acc[bi][oi]     += u[bi] * a[oi];
                    acc[bi][4 + oi] += u[bi] * b2[oi];
                }
        }
        __syncthreads();
    }

    float bs[8];
    #pragma unroll
    for (int oi = 0; oi < 4; ++oi) {
        bs[oi]     = bias[((tx * 4 + oi) << 10) + l];
        bs[4 + oi] = bias[((tx * 4 + 64 + oi) << 10) + l];
    }
    #pragma unroll
    for (int bi = 0; bi < 4; ++bi) {
        const int b = ty * 4 + bi;
        #pragma unroll
        for (int oi = 0; oi < 4; ++oi) {
            out[((b * 128 + tx * 4 + oi) << 10) + l]      = acc[bi][oi]     + bs[oi];
            out[((b * 128 + tx * 4 + 64 + oi) << 10) + l] = acc[bi][4 + oi] + bs[4 + oi];
        }
    }
}

// ---------------------------------------------------------------- launch
extern "C" void kernel_launch(void* const* d_in, const int* in_sizes, int n_in,
                              void* d_out, int out_size, void* d_ws, size_t ws_size,
                              hipStream_t stream) {
    const float* x    = (const float*)d_in[0];
    const float* w    = (const float*)d_in[1];
    const float* bias = (const float*)d_in[2];
    float* out        = (float*)d_out;

    const size_t UA_BYTES  = 75497472ull;   // 32*4*18*4*8192
    const size_t WS1_BYTES = 33554432ull;   // 64*128*1024 * 4

    if (d_ws && ws_size >= UA_BYTES + 2 * WS1_BYTES) {
        unsigned short* uab = (unsigned short*)d_ws;
        float* wso = (float*)((char*)d_ws + UA_BYTES);
        u_kernel<<<dim3(256), dim3(256), 0, stream>>>(x, uab);
        mfma_kernel<true, true><<<dim3(2048), dim3(512), 0, stream>>>(uab, w, bias, wso, out);
        out_kernel<2><<<dim3(1024), dim3(256), 0, stream>>>(wso, bias, out);
    } else if (d_ws && ws_size >= UA_BYTES + WS1_BYTES) {
        unsigned short* uab = (unsigned short*)d_ws;
        float* wso = (float*)((char*)d_ws + UA_BYTES);
        u_kernel<<<dim3(256), dim3(256), 0, stream>>>(x, uab);
        mfma_kernel<true, false><<<dim3(1024), dim3(512), 0, stream>>>(uab, w, bias, wso, out);
        out_kernel<1><<<dim3(1024), dim3(256), 0, stream>>>(wso, bias, out);
    } else if (d_ws && ws_size >= UA_BYTES) {
        unsigned short* uab = (unsigned short*)d_ws;
        u_kernel<<<dim3(256), dim3(256), 0, stream>>>(x, uab);
        mfma_kernel<false, false><<<dim3(1024), dim3(512), 0, stream>>>(uab, w, bias, nullptr, out);
    } else {
        lc2d_fp32<<<dim3(1024), dim3(256), 0, stream>>>(x, w, bias, out);
    }
}

// Round 8
// 151.002 us; speedup vs baseline: 2.2635x; 1.0804x over previous
//
#include <hip/hip_runtime.h>
#include <hip/hip_bf16.h>

// TransposedLocallyConnected2D: out[b,o,l] = sum_d U[b,d,l] * W[d,l,o] + bias[o,l]
//   B=64, C=64, OC=128, L=1024, D=576 (d = c*9 + ii*3 + jj). Per-l 64x128x576 GEMM.
//
// R8: R7 proved line-optimal fragment layouts + 32 waves/CU fixed the request
// stall (kernels dropped below the harness memsets in the profile). Now cut pure
// traffic: replace split-K (which doubled the ws slab: 67MB w + 67MB r) with
// split-O (o-halves) -> NO partial sums, single 34MB ws slab, same 2048-block
// dispatch granularity. W still read exactly once (disjoint 256B line-aligned
// halves); uA slice (73KB/l) may be fetched twice but the two o-half blocks are
// XCD-adjacent -> second read is an L2 hit.
//
// uA byte layout: cell[(oh*4+mt)*18 + kt][g] of 8192B, inside: (ow*16 + r)*16.
//   uA frag(mt,kt,g,r | l) = U[b=16mt+r][k=32kt+8g+e][l], e=0..7 (bf16 us8).

typedef __attribute__((ext_vector_type(8))) short bf16x8;
typedef __attribute__((ext_vector_type(4))) float f32x4;
typedef __attribute__((ext_vector_type(4))) unsigned short us4;
typedef __attribute__((ext_vector_type(8))) unsigned short us8;

__device__ __forceinline__ unsigned short f2bf(float f) {
    union { __hip_bfloat16 h; unsigned short u; } cv;
    cv.h = __float2bfloat16(f);
    return cv.u;
}

// ---------------------------------------------------------------- kernel 1
// grid 256: blk -> ch (c-half), bg (b-quarter = mt), oh.  (R7-verified)
__global__ __launch_bounds__(256, 1)
void u_kernel(const float* __restrict__ x, unsigned short* __restrict__ uA)
{
    __shared__ unsigned short xs[3 * 32 * 16 * 36];   // [y][c][b][32z + 4 pad]

    const int blk = blockIdx.x;
    const int ch = blk & 1;          // c in [32ch, 32ch+32)
    const int bg = (blk >> 1) & 3;   // b in [16bg, 16bg+16)  (mt = bg)
    const int oh = blk >> 3;
    const int t  = threadIdx.x;

    // ---- stage x chunk: 16b x 32c x 3y x 32z, fully coalesced float4
    #pragma unroll
    for (int y = 0; y < 3; ++y) {
        const int yg = oh - 1 + y;
        const bool rowok = (unsigned)yg < 32u;   // block-uniform
        #pragma unroll
        for (int j = 0; j < 16; ++j) {
            const int idx2 = t + 256 * j;
            const int z4 = idx2 & 7;
            const int cl = (idx2 >> 3) & 31;
            const int bl = idx2 >> 8;
            float4 v = {0.f, 0.f, 0.f, 0.f};
            if (rowok)
                v = *(const float4*)(x + ((((16 * bg + bl) * 64 + 32 * ch + cl) * 32 + yg) << 5) + 4 * z4);
            *(us4*)&xs[((y * 32 + cl) * 16 + bl) * 36 + 4 * z4] =
                (us4){f2bf(v.x), f2bf(v.y), f2bf(v.z), f2bf(v.w)};
        }
    }
    __syncthreads();

    // ---- gather: item (bl = t&15, ow = t>>4 + 16p)  -> 1KB-contiguous wave stores
    const int bl = t & 15;
    #pragma unroll
    for (int p = 0; p < 2; ++p) {
        const int ow = (t >> 4) + 16 * p;
        #pragma unroll
        for (int cc = 0; cc < 2; ++cc) {
            us8 arr[18];
            #pragma unroll
            for (int c16 = 0; c16 < 16; ++c16) {
                const int c = cc * 16 + c16;
                #pragma unroll
                for (int ii = 0; ii < 3; ++ii) {
                    const unsigned short* xr = &xs[((ii * 32 + c) * 16 + bl) * 36];
                    const unsigned short vm = (ow > 0)  ? xr[ow - 1] : (unsigned short)0;
                    const unsigned short v0 = xr[ow];
                    const unsigned short vp = (ow < 31) ? xr[ow + 1] : (unsigned short)0;
                    const int f = c16 * 9 + ii * 3;      // compile-time after unroll
                    arr[(f + 0) >> 3][(f + 0) & 7] = vm;
                    arr[(f + 1) >> 3][(f + 1) & 7] = v0;
                    arr[(f + 2) >> 3][(f + 2) & 7] = vp;
                }
            }
            // ks = 36ch + 18cc + j; kt = ks>>2, g = ks&3
            char* base = (char*)uA + (size_t)(oh * 4 + bg) * 589824 + (ow * 16 + bl) * 16;
            #pragma unroll
            for (int j = 0; j < 18; ++j) {
                const int ks = 36 * ch + 18 * cc + j;
                *(us8*)(base + (size_t)(ks >> 2) * 32768 + (size_t)(ks & 3) * 8192) = arr[j];
            }
        }
    }
}

// ---------------------------------------------------------------- kernel 2
// 256 threads = 4 waves; grid 2048 = 2 o-halves x 1024 l.
// Wave wvn owns o = 64*ohf + 16*wvn + r; acc[4] = 4 mt (full b). Full K (18 kt).
template <bool WSPATH>
__global__ __launch_bounds__(256, 8)
void mfma_kernel(const unsigned short* __restrict__ uA,
                 const float* __restrict__ w,
                 const float* __restrict__ bias,
                 float* __restrict__ wsout,
                 float* __restrict__ out)
{
    const int blk  = blockIdx.x;
    const int ohf  = blk & 1;              // o-half
    const int lq   = blk >> 1;
    const int l    = ((lq & 7) << 7) | (lq >> 3);   // bijective XCD swizzle
    const int oh   = l >> 5, ow = l & 31;
    const int tid  = threadIdx.x;
    const int lane = tid & 63;
    const int wvn  = tid >> 6;      // 0..3
    const int r    = lane & 15;
    const int g    = lane >> 4;
    const int o    = 64 * ohf + 16 * wvn + r;

    // W: lane(r,g) reads W[d = 32ktl + 8g + i][l][o]
    const float* wp = w + (size_t)(8 * g) * 131072 + (size_t)l * 128 + o;
    // uA: 4-segment fragment reads (256B per 16-lane group)
    const char* up = (const char*)uA + (size_t)(oh * 4) * 589824
                     + g * 8192 + (ow * 16 + r) * 16;

    f32x4 acc[4];
    #pragma unroll
    for (int mt = 0; mt < 4; ++mt) acc[mt] = (f32x4){0.f, 0.f, 0.f, 0.f};

    #pragma unroll
    for (int ktl = 0; ktl < 18; ++ktl) {
        bf16x8 cu[4];
        #pragma unroll
        for (int mt = 0; mt < 4; ++mt)
            cu[mt] = *(const bf16x8*)(up + (size_t)mt * 589824 + (size_t)ktl * 32768);
        us8 fb;
        #pragma unroll
        for (int i = 0; i < 8; ++i)
            fb[i] = f2bf(wp[(size_t)(ktl * 32 + i) * 131072]);
        union { us8 u; bf16x8 b; } cb;
        cb.u = fb;
        #pragma unroll
        for (int mt = 0; mt < 4; ++mt)
            acc[mt] = __builtin_amdgcn_mfma_f32_16x16x32_bf16(cu[mt], cb.b, acc[mt], 0, 0, 0);
    }

    // epilogue: acc[mt] elem q -> b = 16mt + 4g + q, o fixed per lane
    if (WSPATH) {
        float* wsp = wsout + ((size_t)l << 13) + o * 64 + 4 * g;
        #pragma unroll
        for (int mt = 0; mt < 4; ++mt)
            *(f32x4*)(wsp + 16 * mt) = acc[mt];
    } else {
        const float bz = bias[(o << 10) + l];
        #pragma unroll
        for (int mt = 0; mt < 4; ++mt)
            #pragma unroll
            for (int q = 0; q < 4; ++q) {
                const int b = 16 * mt + 4 * g + q;
                out[((size_t)(b * 128 + o) << 10) + l] = acc[mt][q] + bz;
            }
    }
}

// ---------------------------------------------------------------- kernel 3
// ws[l][o][b] -> out[b][o][l] (+bias), tiles [32 l][16 o][16 b]  (verified)
__global__ __launch_bounds__(256, 4)
void out_kernel(const float* __restrict__ ws,
                const float* __restrict__ bias,
                float* __restrict__ out)
{
    __shared__ float Ls[32 * 16 * 16];
    const int blk = blockIdx.x;
    const int b0 = (blk & 3) * 16;
    const int o0 = ((blk >> 2) & 7) * 16;
    const int l0 = (blk >> 5) * 32;
    const int t  = threadIdx.x;

    const int b4  = (t & 3) * 4;
    const int o   = (t >> 2) & 15;
    const int lr0 = t >> 6;
    #pragma unroll
    for (int p = 0; p < 8; ++p) {
        const int lr = lr0 + 4 * p;
        const size_t off = (size_t)(l0 + lr) * 8192 + (o0 + o) * 64 + b0 + b4;
        const f32x4 v = *(const f32x4*)(ws + off);
        *(f32x4*)(&Ls[(lr * 16 + o) * 16 + b4]) = v;
    }
    __syncthreads();

    const int lq = (t & 7) * 4;
    #pragma unroll
    for (int p = 0; p < 8; ++p) {
        const int row   = p * 32 + (t >> 3);
        const int o_loc = row >> 4;
        const int b_loc = row & 15;
        f32x4 v;
        #pragma unroll
        for (int q = 0; q < 4; ++q)
            v[q] = Ls[((lq + q) * 16 + o_loc) * 16 + b_loc];
        const f32x4 bz = *(const f32x4*)(bias + (o0 + o_loc) * 1024 + l0 + lq);
        v += bz;
        *(f32x4*)(out + ((size_t)((b0 + b_loc) * 128) + o0 + o_loc) * 1024 + l0 + lq) = v;
    }
}

// ---------------------------------------------------------------- fp32 fallback (R1-verified)
__global__ __launch_bounds__(256, 4)
void lc2d_fp32(const float* __restrict__ x,
               const float* __restrict__ w,
               const float* __restrict__ bias,
               float* __restrict__ out)
{
    __shared__ float Us[36][68];
    __shared__ float Ws[36][128];
    const int blk = blockIdx.x;
    const int l  = ((blk & 7) << 7) | (blk >> 3);
    const int oh = l >> 5, ow = l & 31;
    const int tid = threadIdx.x;
    const int tx = tid & 15, ty = tid >> 4;
    const int sb = tid >> 2, sc = tid & 3;

    float acc[4][8];
    #pragma unroll
    for (int i = 0; i < 4; ++i)
        #pragma unroll
        for (int j = 0; j < 8; ++j) acc[i][j] = 0.f;

    for (int chn = 0; chn < 16; ++chn) {
        const int c0 = chn * 4;
        const float* xb = x + ((size_t)(sb * 64 + c0 + sc) << 10);
        #pragma unroll
        for (int ii = 0; ii < 3; ++ii) {
            const int y = oh + ii - 1;
            const bool yok = ((unsigned)y < 32u);
            #pragma unroll
            for (int jj = 0; jj < 3; ++jj) {
                const int z = ow + jj - 1;
                float v = 0.f;
                if (yok && ((unsigned)z < 32u)) v = xb[(y << 5) + z];
                Us[sc * 9 + ii * 3 + jj][sb] = v;
            }
        }
        const int dbase = c0 * 9;
        #pragma unroll
        for (int it = 0; it < 5; ++it) {
            const int idx = tid + it * 256;
            if (idx < 36 * 32) {
                const int kk = idx >> 5, o4 = idx & 31;
                const float4 v = *reinterpret_cast<const float4*>(
                    w + (((size_t)(dbase + kk) * 1024 + l) * 128 + o4 * 4));
                *reinterpret_cast<float4*>(&Ws[kk][o4 * 4]) = v;
            }
        }
        __syncthreads();
        #pragma unroll 6
        for (int kk = 0; kk < 36; ++kk) {
            const float4 ub = *reinterpret_cast<const float4*>(&Us[kk][ty * 4]);
            const float4 wa = *reinterpret_cast<const float4*>(&Ws[kk][tx * 4]);
            const float4 wb = *reinterpret_cast<const float4*>(&Ws[kk][tx * 4 + 64]);
            const float u[4]  = {ub.x, ub.y, ub.z, ub.w};
            const float a[4]  = {wa.x, wa.y, wa.z, wa.w};
            const float b2[4] = {wb.x, wb.y, wb.z, wb.w};
            #pragma unroll
            for (int bi = 0; bi < 4; ++bi)
                #pragma unroll
                for (int oi = 0; oi < 4; ++oi) {
                    acc[bi][oi]     += u[bi] * a[oi];
                    acc[bi][4 + oi] += u[bi] * b2[oi];
                }
        }
        __syncthreads();
    }

    float bs[8];
    #pragma unroll
    for (int oi = 0; oi < 4; ++oi) {
        bs[oi]     = bias[((tx * 4 + oi) << 10) + l];
        bs[4 + oi] = bias[((tx * 4 + 64 + oi) << 10) + l];
    }
    #pragma unroll
    for (int bi = 0; bi < 4; ++bi) {
        const int b = ty * 4 + bi;
        #pragma unroll
        for (int oi = 0; oi < 4; ++oi) {
            out[((b * 128 + tx * 4 + oi) << 10) + l]      = acc[bi][oi]     + bs[oi];
            out[((b * 128 + tx * 4 + 64 + oi) << 10) + l] = acc[bi][4 + oi] + bs[4 + oi];
        }
    }
}

// ---------------------------------------------------------------- launch
extern "C" void kernel_launch(void* const* d_in, const int* in_sizes, int n_in,
                              void* d_out, int out_size, void* d_ws, size_t ws_size,
                              hipStream_t stream) {
    const float* x    = (const float*)d_in[0];
    const float* w    = (const float*)d_in[1];
    const float* bias = (const float*)d_in[2];
    float* out        = (float*)d_out;

    const size_t UA_BYTES  = 75497472ull;   // 32*4*18*4*8192
    const size_t WS1_BYTES = 33554432ull;   // 64*128*1024 * 4

    if (d_ws && ws_size >= UA_BYTES + WS1_BYTES) {
        unsigned short* uab = (unsigned short*)d_ws;
        float* wso = (float*)((char*)d_ws + UA_BYTES);
        u_kernel<<<dim3(256), dim3(256), 0, stream>>>(x, uab);
        mfma_kernel<true><<<dim3(2048), dim3(256), 0, stream>>>(uab, w, bias, wso, out);
        out_kernel<<<dim3(1024), dim3(256), 0, stream>>>(wso, bias, out);
    } else if (d_ws && ws_size >= UA_BYTES) {
        unsigned short* uab = (unsigned short*)d_ws;
        u_kernel<<<dim3(256), dim3(256), 0, stream>>>(x, uab);
        mfma_kernel<false><<<dim3(2048), dim3(256), 0, stream>>>(uab, w, bias, nullptr, out);
    } else {
        lc2d_fp32<<<dim3(1024), dim3(256), 0, stream>>>(x, w, bias, out);
    }
}

// Round 9
// 146.870 us; speedup vs baseline: 2.3272x; 1.0281x over previous
//
#include <hip/hip_runtime.h>
#include <hip/hip_bf16.h>

// TransposedLocallyConnected2D: out[b,o,l] = sum_d U[b,d,l] * W[d,l,o] + bias[o,l]
//   B=64, C=64, OC=128, L=1024, D=576 (d = c*9 + ii*3 + jj). Per-l 64x128x576 GEMM.
//
// R9 (on R8's verified maps): mfma_kernel v3.
//  - 1024 blocks x 512 thr (8 waves); wave wvn owns o = 16*wvn + r; full K.
//    (R8's o-half blocks landed on different XCDs -> uA double-fetched from HBM.)
//  - saddr addressing: uniform SGPR bases stepped by compile-time consts per kt;
//    per-lane u32 offsets constant through the loop -> ~0 VALU address math.
//  - W f32->bf16 via v_cvt_pk_bf16_f32 (T12 recipe: src0->lo) -> 4 VALU/kt.
//
// uA byte layout: cell[(oh*4+mt)*18 + kt][g] of 8192B, inside: (ow*16 + r)*16.
//   uA frag(mt,kt,g,r | l) = U[b=16mt+r][k=32kt+8g+e][l], e=0..7 (bf16 us8).

typedef __attribute__((ext_vector_type(8))) short bf16x8;
typedef __attribute__((ext_vector_type(4))) float f32x4;
typedef __attribute__((ext_vector_type(4))) unsigned short us4;
typedef __attribute__((ext_vector_type(8))) unsigned short us8;

__device__ __forceinline__ unsigned short f2bf(float f) {
    union { __hip_bfloat16 h; unsigned short u; } cv;
    cv.h = __float2bfloat16(f);
    return cv.u;
}

// ---------------------------------------------------------------- kernel 1
// grid 256: blk -> ch (c-half), bg (b-quarter = mt), oh.  (R7/R8-verified)
__global__ __launch_bounds__(256, 1)
void u_kernel(const float* __restrict__ x, unsigned short* __restrict__ uA)
{
    __shared__ unsigned short xs[3 * 32 * 16 * 36];   // [y][c][b][32z + 4 pad]

    const int blk = blockIdx.x;
    const int ch = blk & 1;          // c in [32ch, 32ch+32)
    const int bg = (blk >> 1) & 3;   // b in [16bg, 16bg+16)  (mt = bg)
    const int oh = blk >> 3;
    const int t  = threadIdx.x;

    // ---- stage x chunk: 16b x 32c x 3y x 32z, fully coalesced float4
    #pragma unroll
    for (int y = 0; y < 3; ++y) {
        const int yg = oh - 1 + y;
        const bool rowok = (unsigned)yg < 32u;   // block-uniform
        #pragma unroll
        for (int j = 0; j < 16; ++j) {
            const int idx2 = t + 256 * j;
            const int z4 = idx2 & 7;
            const int cl = (idx2 >> 3) & 31;
            const int bl = idx2 >> 8;
            float4 v = {0.f, 0.f, 0.f, 0.f};
            if (rowok)
                v = *(const float4*)(x + ((((16 * bg + bl) * 64 + 32 * ch + cl) * 32 + yg) << 5) + 4 * z4);
            *(us4*)&xs[((y * 32 + cl) * 16 + bl) * 36 + 4 * z4] =
                (us4){f2bf(v.x), f2bf(v.y), f2bf(v.z), f2bf(v.w)};
        }
    }
    __syncthreads();

    // ---- gather: item (bl = t&15, ow = t>>4 + 16p)  -> 1KB-contiguous wave stores
    const int bl = t & 15;
    #pragma unroll
    for (int p = 0; p < 2; ++p) {
        const int ow = (t >> 4) + 16 * p;
        #pragma unroll
        for (int cc = 0; cc < 2; ++cc) {
            us8 arr[18];
            #pragma unroll
            for (int c16 = 0; c16 < 16; ++c16) {
                const int c = cc * 16 + c16;
                #pragma unroll
                for (int ii = 0; ii < 3; ++ii) {
                    const unsigned short* xr = &xs[((ii * 32 + c) * 16 + bl) * 36];
                    const unsigned short vm = (ow > 0)  ? xr[ow - 1] : (unsigned short)0;
                    const unsigned short v0 = xr[ow];
                    const unsigned short vp = (ow < 31) ? xr[ow + 1] : (unsigned short)0;
                    const int f = c16 * 9 + ii * 3;      // compile-time after unroll
                    arr[(f + 0) >> 3][(f + 0) & 7] = vm;
                    arr[(f + 1) >> 3][(f + 1) & 7] = v0;
                    arr[(f + 2) >> 3][(f + 2) & 7] = vp;
                }
            }
            // ks = 36ch + 18cc + j; kt = ks>>2, g = ks&3
            char* base = (char*)uA + (size_t)(oh * 4 + bg) * 589824 + (ow * 16 + bl) * 16;
            #pragma unroll
            for (int j = 0; j < 18; ++j) {
                const int ks = 36 * ch + 18 * cc + j;
                *(us8*)(base + (size_t)(ks >> 2) * 32768 + (size_t)(ks & 3) * 8192) = arr[j];
            }
        }
    }
}

// ---------------------------------------------------------------- kernel 2
// 512 threads = 8 waves; grid 1024 = one block per l (covers all 128 o).
// Wave wvn owns o = 16*wvn + r; acc[4] = 4 mt (full b). Full K (18 kt).
template <bool WSPATH>
__global__ __launch_bounds__(512, 8)
void mfma_kernel(const unsigned short* __restrict__ uA,
                 const float* __restrict__ w,
                 const float* __restrict__ bias,
                 float* __restrict__ wsout,
                 float* __restrict__ out)
{
    const int blk  = blockIdx.x;
    const int l    = ((blk & 7) << 7) | (blk >> 3);   // bijective XCD swizzle
    const int oh   = l >> 5, ow = l & 31;
    const int tid  = threadIdx.x;
    const int lane = tid & 63;
    const int wvn  = tid >> 6;      // 0..7
    const int r    = lane & 15;
    const int g    = lane >> 4;
    const int o    = 16 * wvn + r;

    // uniform SGPR bases (stepped by compile-time constants per kt)
    const char* ubase = (const char*)uA + (size_t)oh * 2359296;   // oh * 4*18*32768
    const char* wbase = (const char*)w  + (size_t)l * 512;

    // per-lane u32 offsets, constant through the k-loop
    const unsigned uoff = (unsigned)(g * 8192 + (ow * 16 + r) * 16);
    unsigned woff[8];
    #pragma unroll
    for (int i = 0; i < 8; ++i)
        woff[i] = (unsigned)(((8 * g + i) * 131072 + o) * 4);     // <= ~16.5 MB

    f32x4 acc[4];
    #pragma unroll
    for (int mt = 0; mt < 4; ++mt) acc[mt] = (f32x4){0.f, 0.f, 0.f, 0.f};

    #pragma unroll
    for (int ktl = 0; ktl < 18; ++ktl) {
        const char* ub_kt = ubase + ktl * 32768;
        const char* wb_kt = wbase + (size_t)ktl * 16777216;       // 32*131072*4

        bf16x8 cu[4];
        #pragma unroll
        for (int mt = 0; mt < 4; ++mt)
            cu[mt] = *(const bf16x8*)(ub_kt + mt * 589824 + uoff);

        float wf[8];
        #pragma unroll
        for (int i = 0; i < 8; ++i)
            wf[i] = *(const float*)(wb_kt + woff[i]);

        union { unsigned u[4]; bf16x8 b; } cb;
        #pragma unroll
        for (int j = 0; j < 4; ++j)
            asm("v_cvt_pk_bf16_f32 %0, %1, %2"
                : "=v"(cb.u[j]) : "v"(wf[2 * j]), "v"(wf[2 * j + 1]));

        #pragma unroll
        for (int mt = 0; mt < 4; ++mt)
            acc[mt] = __builtin_amdgcn_mfma_f32_16x16x32_bf16(cu[mt], cb.b, acc[mt], 0, 0, 0);
    }

    // epilogue: acc[mt] elem q -> b = 16mt + 4g + q, o fixed per lane
    if (WSPATH) {
        float* wsp = wsout + ((size_t)l << 13) + o * 64 + 4 * g;
        #pragma unroll
        for (int mt = 0; mt < 4; ++mt)
            *(f32x4*)(wsp + 16 * mt) = acc[mt];
    } else {
        const float bz = bias[(o << 10) + l];
        #pragma unroll
        for (int mt = 0; mt < 4; ++mt)
            #pragma unroll
            for (int q = 0; q < 4; ++q) {
                const int b = 16 * mt + 4 * g + q;
                out[((size_t)(b * 128 + o) << 10) + l] = acc[mt][q] + bz;
            }
    }
}

// ---------------------------------------------------------------- kernel 3
// ws[l][o][b] -> out[b][o][l] (+bias), tiles [32 l][16 o][16 b]  (verified)
__global__ __launch_bounds__(256, 4)
void out_kernel(const float* __restrict__ ws,
                const float* __restrict__ bias,
                float* __restrict__ out)
{
    __shared__ float Ls[32 * 16 * 16];
    const int blk = blockIdx.x;
    const int b0 = (blk & 3) * 16;
    const int o0 = ((blk >> 2) & 7) * 16;
    const int l0 = (blk >> 5) * 32;
    const int t  = threadIdx.x;

    const int b4  = (t & 3) * 4;
    const int o   = (t >> 2) & 15;
    const int lr0 = t >> 6;
    #pragma unroll
    for (int p = 0; p < 8; ++p) {
        const int lr = lr0 + 4 * p;
        const size_t off = (size_t)(l0 + lr) * 8192 + (o0 + o) * 64 + b0 + b4;
        const f32x4 v = *(const f32x4*)(ws + off);
        *(f32x4*)(&Ls[(lr * 16 + o) * 16 + b4]) = v;
    }
    __syncthreads();

    const int lq = (t & 7) * 4;
    #pragma unroll
    for (int p = 0; p < 8; ++p) {
        const int row   = p * 32 + (t >> 3);
        const int o_loc = row >> 4;
        const int b_loc = row & 15;
        f32x4 v;
        #pragma unroll
        for (int q = 0; q < 4; ++q)
            v[q] = Ls[((lq + q) * 16 + o_loc) * 16 + b_loc];
        const f32x4 bz = *(const f32x4*)(bias + (o0 + o_loc) * 1024 + l0 + lq);
        v += bz;
        *(f32x4*)(out + ((size_t)((b0 + b_loc) * 128) + o0 + o_loc) * 1024 + l0 + lq) = v;
    }
}

// ---------------------------------------------------------------- fp32 fallback (R1-verified)
__global__ __launch_bounds__(256, 4)
void lc2d_fp32(const float* __restrict__ x,
               const float* __restrict__ w,
               const float* __restrict__ bias,
               float* __restrict__ out)
{
    __shared__ float Us[36][68];
    __shared__ float Ws[36][128];
    const int blk = blockIdx.x;
    const int l  = ((blk & 7) << 7) | (blk >> 3);
    const int oh = l >> 5, ow = l & 31;
    const int tid = threadIdx.x;
    const int tx = tid & 15, ty = tid >> 4;
    const int sb = tid >> 2, sc = tid & 3;

    float acc[4][8];
    #pragma unroll
    for (int i = 0; i < 4; ++i)
        #pragma unroll
        for (int j = 0; j < 8; ++j) acc[i][j] = 0.f;

    for (int chn = 0; chn < 16; ++chn) {
        const int c0 = chn * 4;
        const float* xb = x + ((size_t)(sb * 64 + c0 + sc) << 10);
        #pragma unroll
        for (int ii = 0; ii < 3; ++ii) {
            const int y = oh + ii - 1;
            const bool yok = ((unsigned)y < 32u);
            #pragma unroll
            for (int jj = 0; jj < 3; ++jj) {
                const int z = ow + jj - 1;
                float v = 0.f;
                if (yok && ((unsigned)z < 32u)) v = xb[(y << 5) + z];
                Us[sc * 9 + ii * 3 + jj][sb] = v;
            }
        }
        const int dbase = c0 * 9;
        #pragma unroll
        for (int it = 0; it < 5; ++it) {
            const int idx = tid + it * 256;
            if (idx < 36 * 32) {
                const int kk = idx >> 5, o4 = idx & 31;
                const float4 v = *reinterpret_cast<const float4*>(
                    w + (((size_t)(dbase + kk) * 1024 + l) * 128 + o4 * 4));
                *reinterpret_cast<float4*>(&Ws[kk][o4 * 4]) = v;
            }
        }
        __syncthreads();
        #pragma unroll 6
        for (int kk = 0; kk < 36; ++kk) {
            const float4 ub = *reinterpret_cast<const float4*>(&Us[kk][ty * 4]);
            const float4 wa = *reinterpret_cast<const float4*>(&Ws[kk][tx * 4]);
            const float4 wb = *reinterpret_cast<const float4*>(&Ws[kk][tx * 4 + 64]);
            const float u[4]  = {ub.x, ub.y, ub.z, ub.w};
            const float a[4]  = {wa.x, wa.y, wa.z, wa.w};
            const float b2[4] = {wb.x, wb.y, wb.z, wb.w};
            #pragma unroll
            for (int bi = 0; bi < 4; ++bi)
                #pragma unroll
                for (int oi = 0; oi < 4; ++oi) {
                    acc[bi][oi]     += u[bi] * a[oi];
                    acc[bi][4 + oi] += u[bi] * b2[oi];
                }
        }
        __syncthreads();
    }

    float bs[8];
    #pragma unroll
    for (int oi = 0; oi < 4; ++oi) {
        bs[oi]     = bias[((tx * 4 + oi) << 10) + l];
        bs[4 + oi] = bias[((tx * 4 + 64 + oi) << 10) + l];
    }
    #pragma unroll
    for (int bi = 0; bi < 4; ++bi) {
        const int b = ty * 4 + bi;
        #pragma unroll
        for (int oi = 0; oi < 4; ++oi) {
            out[((b * 128 + tx * 4 + oi) << 10) + l]      = acc[bi][oi]     + bs[oi];
            out[((b * 128 + tx * 4 + 64 + oi) << 10) + l] = acc[bi][4 + oi] + bs[4 + oi];
        }
    }
}

// ---------------------------------------------------------------- launch
extern "C" void kernel_launch(void* const* d_in, const int* in_sizes, int n_in,
                              void* d_out, int out_size, void* d_ws, size_t ws_size,
                              hipStream_t stream) {
    const float* x    = (const float*)d_in[0];
    const float* w    = (const float*)d_in[1];
    const float* bias = (const float*)d_in[2];
    float* out        = (float*)d_out;

    const size_t UA_BYTES  = 75497472ull;   // 32*4*18*4*8192
    const size_t WS1_BYTES = 33554432ull;   // 64*128*1024 * 4

    if (d_ws && ws_size >= UA_BYTES + WS1_BYTES) {
        unsigned short* uab = (unsigned short*)d_ws;
        float* wso = (float*)((char*)d_ws + UA_BYTES);
        u_kernel<<<dim3(256), dim3(256), 0, stream>>>(x, uab);
        mfma_kernel<true><<<dim3(1024), dim3(512), 0, stream>>>(uab, w, bias, wso, out);
        out_kernel<<<dim3(1024), dim3(256), 0, stream>>>(wso, bias, out);
    } else if (d_ws && ws_size >= UA_BYTES) {
        unsigned short* uab = (unsigned short*)d_ws;
        u_kernel<<<dim3(256), dim3(256), 0, stream>>>(x, uab);
        mfma_kernel<false><<<dim3(1024), dim3(512), 0, stream>>>(uab, w, bias, nullptr, out);
    } else {
        lc2d_fp32<<<dim3(1024), dim3(256), 0, stream>>>(x, w, bias, out);
    }
}

// Round 10
// 143.678 us; speedup vs baseline: 2.3789x; 1.0222x over previous
//
#include <hip/hip_runtime.h>
#include <hip/hip_bf16.h>

// TransposedLocallyConnected2D: out[b,o,l] = sum_d U[b,d,l] * W[d,l,o] + bias[o,l]
//   B=64, C=64, OC=128, L=1024, D=576 (d = c*9 + ii*3 + jj). Per-l 64x128x576 GEMM.
//
// R10: mfma v4 — 4 l's per block, 1024 threads, 1 block/CU (grid 256).
//  - W reads become 2KB-contiguous per d-row (4x DRAM burst density vs R9).
//  - launch_bounds(1024,1): VGPR cap ~256 (use ~110) -> compiler can software-
//    pipeline the unrolled 18-kt loop (R9's 64-cap forbade any prefetch).
//  - wave wvn: lsub = wvn&3 (l = l0+lsub), wq = wvn>>2; o = 32wq + 16n + r (n=0,1).
//  - uA fragment cell layout unchanged (R7/R8/R9-verified):
//    uA frag(mt,kt,g,r | l) = U[b=16mt+r][k=32kt+8g+e][l], e=0..7 (bf16 us8)
//    at byte ((oh*4+mt)*18+kt)*32768 + g*8192 + (ow*16+r)*16.
//  - epilogue ws[l][o][b] full-line stores (verified) + out_kernel (verified).

typedef __attribute__((ext_vector_type(8))) short bf16x8;
typedef __attribute__((ext_vector_type(4))) float f32x4;
typedef __attribute__((ext_vector_type(4))) unsigned short us4;
typedef __attribute__((ext_vector_type(8))) unsigned short us8;

__device__ __forceinline__ unsigned short f2bf(float f) {
    union { __hip_bfloat16 h; unsigned short u; } cv;
    cv.h = __float2bfloat16(f);
    return cv.u;
}

// ---------------------------------------------------------------- kernel 1
// grid 256: blk -> ch (c-half), bg (b-quarter = mt), oh.  (R7/R8/R9-verified)
__global__ __launch_bounds__(256, 1)
void u_kernel(const float* __restrict__ x, unsigned short* __restrict__ uA)
{
    __shared__ unsigned short xs[3 * 32 * 16 * 36];   // [y][c][b][32z + 4 pad]

    const int blk = blockIdx.x;
    const int ch = blk & 1;          // c in [32ch, 32ch+32)
    const int bg = (blk >> 1) & 3;   // b in [16bg, 16bg+16)  (mt = bg)
    const int oh = blk >> 3;
    const int t  = threadIdx.x;

    // ---- stage x chunk: 16b x 32c x 3y x 32z, fully coalesced float4
    #pragma unroll
    for (int y = 0; y < 3; ++y) {
        const int yg = oh - 1 + y;
        const bool rowok = (unsigned)yg < 32u;   // block-uniform
        #pragma unroll
        for (int j = 0; j < 16; ++j) {
            const int idx2 = t + 256 * j;
            const int z4 = idx2 & 7;
            const int cl = (idx2 >> 3) & 31;
            const int bl = idx2 >> 8;
            float4 v = {0.f, 0.f, 0.f, 0.f};
            if (rowok)
                v = *(const float4*)(x + ((((16 * bg + bl) * 64 + 32 * ch + cl) * 32 + yg) << 5) + 4 * z4);
            *(us4*)&xs[((y * 32 + cl) * 16 + bl) * 36 + 4 * z4] =
                (us4){f2bf(v.x), f2bf(v.y), f2bf(v.z), f2bf(v.w)};
        }
    }
    __syncthreads();

    // ---- gather: item (bl = t&15, ow = t>>4 + 16p)  -> 1KB-contiguous wave stores
    const int bl = t & 15;
    #pragma unroll
    for (int p = 0; p < 2; ++p) {
        const int ow = (t >> 4) + 16 * p;
        #pragma unroll
        for (int cc = 0; cc < 2; ++cc) {
            us8 arr[18];
            #pragma unroll
            for (int c16 = 0; c16 < 16; ++c16) {
                const int c = cc * 16 + c16;
                #pragma unroll
                for (int ii = 0; ii < 3; ++ii) {
                    const unsigned short* xr = &xs[((ii * 32 + c) * 16 + bl) * 36];
                    const unsigned short vm = (ow > 0)  ? xr[ow - 1] : (unsigned short)0;
                    const unsigned short v0 = xr[ow];
                    const unsigned short vp = (ow < 31) ? xr[ow + 1] : (unsigned short)0;
                    const int f = c16 * 9 + ii * 3;      // compile-time after unroll
                    arr[(f + 0) >> 3][(f + 0) & 7] = vm;
                    arr[(f + 1) >> 3][(f + 1) & 7] = v0;
                    arr[(f + 2) >> 3][(f + 2) & 7] = vp;
                }
            }
            // ks = 36ch + 18cc + j; kt = ks>>2, g = ks&3
            char* base = (char*)uA + (size_t)(oh * 4 + bg) * 589824 + (ow * 16 + bl) * 16;
            #pragma unroll
            for (int j = 0; j < 18; ++j) {
                const int ks = 36 * ch + 18 * cc + j;
                *(us8*)(base + (size_t)(ks >> 2) * 32768 + (size_t)(ks & 3) * 8192) = arr[j];
            }
        }
    }
}

// ---------------------------------------------------------------- kernel 2
// 1024 threads = 16 waves; grid 256 = one block per 4 l's (1 block/CU).
// wave wvn: lsub = wvn&3 -> l = l0+lsub; wq = wvn>>2 -> o = 32wq+16n+r, n=0,1.
// acc[4][2] = 4 mt x 2 nt. Full K (18 kt).
template <bool WSPATH>
__global__ __launch_bounds__(1024, 1)
void mfma_kernel(const unsigned short* __restrict__ uA,
                 const float* __restrict__ w,
                 const float* __restrict__ bias,
                 float* __restrict__ wsout,
                 float* __restrict__ out)
{
    const int blk  = blockIdx.x;
    const int lt   = ((blk & 7) << 5) | (blk >> 3);   // bijective XCD swizzle (8x32)
    const int l0   = lt * 4;
    const int oh   = l0 >> 5;
    const int ow0  = l0 & 31;
    const int tid  = threadIdx.x;
    const int lane = tid & 63;
    const int wvn  = tid >> 6;      // 0..15
    const int lsub = wvn & 3;
    const int wq   = wvn >> 2;      // 0..3
    const int r    = lane & 15;
    const int g    = lane >> 4;
    const int l    = l0 + lsub;
    const int ow   = ow0 + lsub;

    // uniform SGPR bases (stepped by compile-time constants per kt)
    const char* ubase = (const char*)uA + (size_t)oh * 2359296;   // oh * 4*18*32768
    const char* wbase = (const char*)w  + (size_t)l * 512;

    // per-lane u32 offsets, constant through the k-loop
    const unsigned uoff = (unsigned)(g * 8192 + (ow * 16 + r) * 16);
    unsigned woff[2][8];
    #pragma unroll
    for (int n = 0; n < 2; ++n)
        #pragma unroll
        for (int i = 0; i < 8; ++i)
            woff[n][i] = (unsigned)((8 * g + i) * 524288 + (32 * wq + 16 * n + r) * 4);

    f32x4 acc[4][2];
    #pragma unroll
    for (int mt = 0; mt < 4; ++mt) {
        acc[mt][0] = (f32x4){0.f, 0.f, 0.f, 0.f};
        acc[mt][1] = (f32x4){0.f, 0.f, 0.f, 0.f};
    }

    #pragma unroll
    for (int ktl = 0; ktl < 18; ++ktl) {
        const char* ub_kt = ubase + ktl * 32768;
        const char* wb_kt = wbase + (size_t)ktl * 16777216;       // 32*131072*4

        bf16x8 cu[4];
        #pragma unroll
        for (int mt = 0; mt < 4; ++mt)
            cu[mt] = *(const bf16x8*)(ub_kt + mt * 589824 + uoff);

        float wf[2][8];
        #pragma unroll
        for (int n = 0; n < 2; ++n)
            #pragma unroll
            for (int i = 0; i < 8; ++i)
                wf[n][i] = *(const float*)(wb_kt + woff[n][i]);

        union { unsigned u[4]; bf16x8 b; } cb[2];
        #pragma unroll
        for (int n = 0; n < 2; ++n)
            #pragma unroll
            for (int j = 0; j < 4; ++j)
                asm("v_cvt_pk_bf16_f32 %0, %1, %2"
                    : "=v"(cb[n].u[j]) : "v"(wf[n][2 * j]), "v"(wf[n][2 * j + 1]));

        #pragma unroll
        for (int mt = 0; mt < 4; ++mt) {
            acc[mt][0] = __builtin_amdgcn_mfma_f32_16x16x32_bf16(cu[mt], cb[0].b, acc[mt][0], 0, 0, 0);
            acc[mt][1] = __builtin_amdgcn_mfma_f32_16x16x32_bf16(cu[mt], cb[1].b, acc[mt][1], 0, 0, 0);
        }
    }

    // epilogue: acc[mt][n] elem q -> b = 16mt + 4g + q, o = 32wq + 16n + r, at l
    if (WSPATH) {
        float* wsp = wsout + ((size_t)l << 13) + 4 * g;
        #pragma unroll
        for (int n = 0; n < 2; ++n) {
            const int o = 32 * wq + 16 * n + r;
            #pragma unroll
            for (int mt = 0; mt < 4; ++mt)
                *(f32x4*)(wsp + o * 64 + 16 * mt) = acc[mt][n];
        }
    } else {
        #pragma unroll
        for (int n = 0; n < 2; ++n) {
            const int o = 32 * wq + 16 * n + r;
            const float bz = bias[(o << 10) + l];
            #pragma unroll
            for (int mt = 0; mt < 4; ++mt)
                #pragma unroll
                for (int q = 0; q < 4; ++q) {
                    const int b = 16 * mt + 4 * g + q;
                    out[((size_t)(b * 128 + o) << 10) + l] = acc[mt][n][q] + bz;
                }
        }
    }
}

// ---------------------------------------------------------------- kernel 3
// ws[l][o][b] -> out[b][o][l] (+bias), tiles [32 l][16 o][16 b]  (verified)
__global__ __launch_bounds__(256, 4)
void out_kernel(const float* __restrict__ ws,
                const float* __restrict__ bias,
                float* __restrict__ out)
{
    __shared__ float Ls[32 * 16 * 16];
    const int blk = blockIdx.x;
    const int b0 = (blk & 3) * 16;
    const int o0 = ((blk >> 2) & 7) * 16;
    const int l0 = (blk >> 5) * 32;
    const int t  = threadIdx.x;

    const int b4  = (t & 3) * 4;
    const int o   = (t >> 2) & 15;
    const int lr0 = t >> 6;
    #pragma unroll
    for (int p = 0; p < 8; ++p) {
        const int lr = lr0 + 4 * p;
        const size_t off = (size_t)(l0 + lr) * 8192 + (o0 + o) * 64 + b0 + b4;
        const f32x4 v = *(const f32x4*)(ws + off);
        *(f32x4*)(&Ls[(lr * 16 + o) * 16 + b4]) = v;
    }
    __syncthreads();

    const int lq = (t & 7) * 4;
    #pragma unroll
    for (int p = 0; p < 8; ++p) {
        const int row   = p * 32 + (t >> 3);
        const int o_loc = row >> 4;
        const int b_loc = row & 15;
        f32x4 v;
        #pragma unroll
        for (int q = 0; q < 4; ++q)
            v[q] = Ls[((lq + q) * 16 + o_loc) * 16 + b_loc];
        const f32x4 bz = *(const f32x4*)(bias + (o0 + o_loc) * 1024 + l0 + lq);
        v += bz;
        *(f32x4*)(out + ((size_t)((b0 + b_loc) * 128) + o0 + o_loc) * 1024 + l0 + lq) = v;
    }
}

// ---------------------------------------------------------------- fp32 fallback (R1-verified)
__global__ __launch_bounds__(256, 4)
void lc2d_fp32(const float* __restrict__ x,
               const float* __restrict__ w,
               const float* __restrict__ bias,
               float* __restrict__ out)
{
    __shared__ float Us[36][68];
    __shared__ float Ws[36][128];
    const int blk = blockIdx.x;
    const int l  = ((blk & 7) << 7) | (blk >> 3);
    const int oh = l >> 5, ow = l & 31;
    const int tid = threadIdx.x;
    const int tx = tid & 15, ty = tid >> 4;
    const int sb = tid >> 2, sc = tid & 3;

    float acc[4][8];
    #pragma unroll
    for (int i = 0; i < 4; ++i)
        #pragma unroll
        for (int j = 0; j < 8; ++j) acc[i][j] = 0.f;

    for (int chn = 0; chn < 16; ++chn) {
        const int c0 = chn * 4;
        const float* xb = x + ((size_t)(sb * 64 + c0 + sc) << 10);
        #pragma unroll
        for (int ii = 0; ii < 3; ++ii) {
            const int y = oh + ii - 1;
            const bool yok = ((unsigned)y < 32u);
            #pragma unroll
            for (int jj = 0; jj < 3; ++jj) {
                const int z = ow + jj - 1;
                float v = 0.f;
                if (yok && ((unsigned)z < 32u)) v = xb[(y << 5) + z];
                Us[sc * 9 + ii * 3 + jj][sb] = v;
            }
        }
        const int dbase = c0 * 9;
        #pragma unroll
        for (int it = 0; it < 5; ++it) {
            const int idx = tid + it * 256;
            if (idx < 36 * 32) {
                const int kk = idx >> 5, o4 = idx & 31;
                const float4 v = *reinterpret_cast<const float4*>(
                    w + (((size_t)(dbase + kk) * 1024 + l) * 128 + o4 * 4));
                *reinterpret_cast<float4*>(&Ws[kk][o4 * 4]) = v;
            }
        }
        __syncthreads();
        #pragma unroll 6
        for (int kk = 0; kk < 36; ++kk) {
            const float4 ub = *reinterpret_cast<const float4*>(&Us[kk][ty * 4]);
            const float4 wa = *reinterpret_cast<const float4*>(&Ws[kk][tx * 4]);
            const float4 wb = *reinterpret_cast<const float4*>(&Ws[kk][tx * 4 + 64]);
            const float u[4]  = {ub.x, ub.y, ub.z, ub.w};
            const float a[4]  = {wa.x, wa.y, wa.z, wa.w};
            const float b2[4] = {wb.x, wb.y, wb.z, wb.w};
            #pragma unroll
            for (int bi = 0; bi < 4; ++bi)
                #pragma unroll
                for (int oi = 0; oi < 4; ++oi) {
                    acc[bi][oi]     += u[bi] * a[oi];
                    acc[bi][4 + oi] += u[bi] * b2[oi];
                }
        }
        __syncthreads();
    }

    float bs[8];
    #pragma unroll
    for (int oi = 0; oi < 4; ++oi) {
        bs[oi]     = bias[((tx * 4 + oi) << 10) + l];
        bs[4 + oi] = bias[((tx * 4 + 64 + oi) << 10) + l];
    }
    #pragma unroll
    for (int bi = 0; bi < 4; ++bi) {
        const int b = ty * 4 + bi;
        #pragma unroll
        for (int oi = 0; oi < 4; ++oi) {
            out[((b * 128 + tx * 4 + oi) << 10) + l]      = acc[bi][oi]     + bs[oi];
            out[((b * 128 + tx * 4 + 64 + oi) << 10) + l] = acc[bi][4 + oi] + bs[4 + oi];
        }
    }
}

// ---------------------------------------------------------------- launch
extern "C" void kernel_launch(void* const* d_in, const int* in_sizes, int n_in,
                              void* d_out, int out_size, void* d_ws, size_t ws_size,
                              hipStream_t stream) {
    const float* x    = (const float*)d_in[0];
    const float* w    = (const float*)d_in[1];
    const float* bias = (const float*)d_in[2];
    float* out        = (float*)d_out;

    const size_t UA_BYTES  = 75497472ull;   // 32*4*18*4*8192
    const size_t WS1_BYTES = 33554432ull;   // 64*128*1024 * 4

    if (d_ws && ws_size >= UA_BYTES + WS1_BYTES) {
        unsigned short* uab = (unsigned short*)d_ws;
        float* wso = (float*)((char*)d_ws + UA_BYTES);
        u_kernel<<<dim3(256), dim3(256), 0, stream>>>(x, uab);
        mfma_kernel<true><<<dim3(256), dim3(1024), 0, stream>>>(uab, w, bias, wso, out);
        out_kernel<<<dim3(1024), dim3(256), 0, stream>>>(wso, bias, out);
    } else if (d_ws && ws_size >= UA_BYTES) {
        unsigned short* uab = (unsigned short*)d_ws;
        u_kernel<<<dim3(256), dim3(256), 0, stream>>>(x, uab);
        mfma_kernel<false><<<dim3(256), dim3(1024), 0, stream>>>(uab, w, bias, nullptr, out);
    } else {
        lc2d_fp32<<<dim3(1024), dim3(256), 0, stream>>>(x, w, bias, out);
    }
}